// Round 7
// baseline (229.448 us; speedup 1.0000x reference)
//
#include <hip/hip_runtime.h>
#include <hip/hip_bf16.h>
#include <math.h>

#define NP 10
#define NE 45
#define TS 16                      // timesteps per block
#define EPB (TS * NE)              // 720 edges per block
#define BLOCK 256
#define NCHUNK ((EPB + 63) / 64)   // 12 chunks of 64 edge-slots

typedef __attribute__((ext_vector_type(8))) short short8;   // 8 bf16 MFMA frag
typedef __attribute__((ext_vector_type(4))) float f32x4;

#define C2LOG2E 2.885390081777927f   // 2*log2(e), folded into W1/W2/b1/b2
#define PI_F    3.14159265358979f
#define PIO2_F  1.57079632679490f

__device__ __forceinline__ float rcp_fast(float x) { return __builtin_amdgcn_rcpf(x); }

// s already scaled by 2*log2(e) and bias-included: tanh = 1 - 2/(2^s + 1)
__device__ __forceinline__ float tanh_pre(float s) {
    float e = __builtin_amdgcn_exp2f(s);
    return fmaf(-2.0f, rcp_fast(e + 1.0f), 1.0f);
}

__device__ __forceinline__ short bf16_rne(float f) {
    unsigned int u = __float_as_uint(f);
    return (short)((u + 0x7fffu + ((u >> 16) & 1u)) >> 16);
}
// pack two floats as bf16x2 (round-half-up) via v_perm: lo = a, hi = b
__device__ __forceinline__ int bf16pk(float a, float b) {
    unsigned int ua = __float_as_uint(a) + 0x8000u;
    unsigned int ub = __float_as_uint(b) + 0x8000u;
    return (int)__builtin_amdgcn_perm(ub, ua, 0x07060302u);
}
__device__ __forceinline__ int bperm_i(int idx_bytes, int v) {
    return __builtin_amdgcn_ds_bpermute(idx_bytes, v);
}

// bf16-accuracy branch-free acos (A&S 4.4.45, |err| < 2e-4 rad)
__device__ __forceinline__ float acos_fast(float w) {
    float a = fabsf(w);
    float s = sqrtf(1.0f - a);
    float p = fmaf(a, fmaf(a, fmaf(a, -0.0187293f, 0.0742610f), -0.2121144f), 1.5707288f);
    float v = s * p;
    return (w >= 0.0f) ? v : PI_F - v;
}
// bf16-accuracy branch-free atan2 (A&S 4.4.49 poly, |err| ~1e-5)
__device__ __forceinline__ float atan2_fast(float y, float x) {
    float ax = fabsf(x), ay = fabsf(y);
    float mx = fmaxf(ax, ay), mn = fminf(ax, ay);
    float t  = mn * rcp_fast(mx);
    float s  = t * t;
    float p  = fmaf(s, fmaf(s, fmaf(s, fmaf(s, 0.0208351f, -0.0851330f),
                                       0.1801410f), -0.3302995f), 0.9998660f);
    float rr = p * t;
    rr = (ay > ax)   ? PIO2_F - rr : rr;
    rr = (x < 0.0f)  ? PI_F  - rr : rr;
    return __builtin_copysignf(rr, y);
}

__global__ __launch_bounds__(BLOCK, 6) void
learn_forces_kernel(const float* __restrict__ D_V, const float* __restrict__ logm,
                    const float* __restrict__ W1, const float* __restrict__ b1,
                    const float* __restrict__ W2, const float* __restrict__ b2,
                    const float* __restrict__ W3, const float* __restrict__ b3,
                    const int* __restrict__ senders, const int* __restrict__ receivers,
                    float* __restrict__ out, int ntime)
{
    __shared__ float einv[NP];
    __shared__ int   stab[NP * 9];            // signed edge list per planet: +-(e+1)
    __shared__ int   mpair[NE];               // packed bf16 (lo=lm_recv, hi=lm_send)
    __shared__ float secart[3][EPB];          // SoA cartesian edge forces (8.64 KB)

    const int tid  = threadIdx.x;
    const int wv   = tid >> 6, lane = tid & 63;
    const int m    = lane & 15, q = lane >> 4;

    if (tid < NP) {
        float l = fminf(12.0f, fmaxf(-12.0f, logm[tid]));
        einv[tid] = __expf(-l);
    }
    if (tid < NE) {
        float lr = fminf(12.0f, fmaxf(-12.0f, logm[receivers[tid]]));
        float ls = fminf(12.0f, fmaxf(-12.0f, logm[senders[tid]]));
        mpair[tid] = bf16pk(lr, ls);
    }
    if (tid < NP) {                           // signed edge table (9 per planet)
        int cnt = 0;
        for (int e = 0; e < NE; ++e) {
            if (receivers[e] == tid) stab[tid * 9 + cnt++] =  (e + 1);
            if (senders[e]   == tid) stab[tid * 9 + cnt++] = -(e + 1);
        }
        for (; cnt < 9; ++cnt) stab[tid * 9 + cnt] = 0;
    }

    // ---- M-permuted weight fragments (invariant: lane's C-regs == next B-frag)
    const int nm = 8 * (m >> 2) + (m & 3);   // + 4t below
    short8 a1[2], a2[2], a3;
    f32x4  cb1[2], cb2[2], cb3;
    #pragma unroll
    for (int t = 0; t < 2; ++t) {
        const int n = nm + 4 * t;
        #pragma unroll
        for (int j = 0; j < 8; ++j) {
            int k = 8 * q + j;
            a1[t][j] = (k < 5) ? bf16_rne(W1[k * 32 + n] * C2LOG2E) : (short)0;
            a2[t][j] = bf16_rne(W2[k * 32 + n] * C2LOG2E);
        }
        #pragma unroll
        for (int r = 0; r < 4; ++r) {
            int nn = 8 * q + 4 * t + r;
            cb1[t][r] = b1[nn] * C2LOG2E;
            cb2[t][r] = b2[nn] * C2LOG2E;
        }
    }
    // L3 with W3 columns replicated across row-quads: A3[row][k] = W3[k][row&3]
    // => every lane's d3[g] regs 0..2 hold (e0,e1,e2) of edge 16g+m directly.
    {
        const int c3 = m & 3;
        #pragma unroll
        for (int j = 0; j < 8; ++j)
            a3[j] = (c3 < 3) ? bf16_rne(W3[(8 * q + j) * 3 + c3]) : (short)0;
        #pragma unroll
        for (int r = 0; r < 4; ++r)
            cb3[r] = (r < 3) ? b3[r] : 0.0f;
    }

    const int bpm = m * 4;                   // bperm idx base: source lane (g<<4)|m
    __syncthreads();

    // software prefetch of first chunk's D_V
    const long ebase = (long)blockIdx.x * EPB;
    float xn = 1.f, yn = 0.f, zn = 0.f;
    {
        int e0i = wv * 64 + lane;
        if (e0i < EPB) {
            const float* dv = D_V + (ebase + e0i) * 3;
            xn = dv[0]; yn = dv[1]; zn = dv[2];
        }
    }

    for (int c = wv; c < NCHUNK; c += 4) {
        const int  e_loc  = c * 64 + lane;
        const bool active = e_loc < EPB;

        float x = xn, y = yn, z = zn;
        // prefetch next chunk
        xn = 1.f; yn = 0.f; zn = 0.f;
        {
            int enx = (c + 4) * 64 + lane;
            if (c + 4 < NCHUNK && enx < EPB) {
                const float* dv = D_V + (ebase + enx) * 3;
                xn = dv[0]; yn = dv[1]; zn = dv[2];
            }
        }

        // ---- own-edge features (fast math, bf16-accuracy) ----------------
        const int le = e_loc % NE;
        float r  = sqrtf(x * x + y * y + z * z);
        float zr = fminf(1.0f, fmaxf(-1.0f, z * rcp_fast(r)));
        float th = acos_fast(zr);
        float ph = atan2_fast(y, x);

        // pack features as bf16 pairs BEFORE transport (3 ints carry 5 features)
        int mp   = mpair[le];                              // lo=lmr, hi=lms
        int p_rt = bf16pk(r, th);                          // k0,k1
        int p_pm = (int)__builtin_amdgcn_perm(             // lo=ph (k2), hi=lmr (k3)
                       (unsigned)mp, __float_as_uint(ph) + 0x8000u, 0x05040302u);
        int p_s0 = ((unsigned)mp) >> 16;                   // lo=lms (k4), hi=0

        // ---- S1: 12 bperms move all 4 groups' B-rows (one latency hop) ---
        int b0[4], b1g[4], b2g[4];
        #pragma unroll
        for (int g = 0; g < 4; ++g) {
            const int idx = bpm + g * 64;
            b0[g]  = bperm_i(idx, p_rt);
            b1g[g] = bperm_i(idx, p_pm);
            b2g[g] = bperm_i(idx, p_s0);
        }

        // ---- S2: L1 MFMAs (A zeros at k>=5 mask garbage B rows) ----------
        f32x4 d0[4], d1[4];
        #pragma unroll
        for (int g = 0; g < 4; ++g) {
            short8 bf1;
            int* bi = (int*)&bf1;
            bi[0] = b0[g]; bi[1] = b1g[g]; bi[2] = b2g[g]; bi[3] = 0;
            d0[g] = __builtin_amdgcn_mfma_f32_16x16x32_bf16(a1[0], bf1, cb1[0], 0, 0, 0);
            d1[g] = __builtin_amdgcn_mfma_f32_16x16x32_bf16(a1[1], bf1, cb1[1], 0, 0, 0);
        }

        // ---- S3: tanh + L2 MFMAs -----------------------------------------
        #pragma unroll
        for (int g = 0; g < 4; ++g) {
            short8 bh;
            int* hb = (int*)&bh;
            float h0 = tanh_pre(d0[g][0]), h1 = tanh_pre(d0[g][1]);
            float h2 = tanh_pre(d0[g][2]), h3 = tanh_pre(d0[g][3]);
            float h4 = tanh_pre(d1[g][0]), h5 = tanh_pre(d1[g][1]);
            float h6 = tanh_pre(d1[g][2]), h7 = tanh_pre(d1[g][3]);
            hb[0] = bf16pk(h0, h1); hb[1] = bf16pk(h2, h3);
            hb[2] = bf16pk(h4, h5); hb[3] = bf16pk(h6, h7);
            d0[g] = __builtin_amdgcn_mfma_f32_16x16x32_bf16(a2[0], bh, cb2[0], 0, 0, 0);
            d1[g] = __builtin_amdgcn_mfma_f32_16x16x32_bf16(a2[1], bh, cb2[1], 0, 0, 0);
        }

        // ---- S4: tanh + L3 MFMAs -----------------------------------------
        f32x4 d3[4];
        #pragma unroll
        for (int g = 0; g < 4; ++g) {
            short8 bh;
            int* hb = (int*)&bh;
            float h0 = tanh_pre(d0[g][0]), h1 = tanh_pre(d0[g][1]);
            float h2 = tanh_pre(d0[g][2]), h3 = tanh_pre(d0[g][3]);
            float h4 = tanh_pre(d1[g][0]), h5 = tanh_pre(d1[g][1]);
            float h6 = tanh_pre(d1[g][2]), h7 = tanh_pre(d1[g][3]);
            hb[0] = bf16pk(h0, h1); hb[1] = bf16pk(h2, h3);
            hb[2] = bf16pk(h4, h5); hb[3] = bf16pk(h6, h7);
            d3[g] = __builtin_amdgcn_mfma_f32_16x16x32_bf16(a3, bh, cb3, 0, 0, 0);
        }

        // ---- S5: own-group register select (no transport needed) ---------
        float e0a = (q & 1) ? d3[1][0] : d3[0][0], e0b = (q & 1) ? d3[3][0] : d3[2][0];
        float e1a = (q & 1) ? d3[1][1] : d3[0][1], e1b = (q & 1) ? d3[3][1] : d3[2][1];
        float e2a = (q & 1) ? d3[1][2] : d3[0][2], e2b = (q & 1) ? d3[3][2] : d3[2][2];
        float e0 = (q & 2) ? e0b : e0a;
        float e1 = (q & 2) ? e1b : e1a;
        float e2 = (q & 2) ? e2b : e2a;

        // ---- sph -> cart, plain SoA LDS store (no atomics) ---------------
        float st = __sinf(e1), ct = __cosf(e1);
        float sp = __sinf(e2), cp = __cosf(e2);
        if (active) {
            secart[0][e_loc] = e0 * st * cp;
            secart[1][e_loc] = e0 * st * sp;
            secart[2][e_loc] = e0 * ct;
        }
    }
    __syncthreads();

    // ---- table-driven signed gather-sum: one (t, planet, comp) per thread
    const long t0g = (long)blockIdx.x * TS;
    for (int i = tid; i < TS * NP * 3; i += BLOCK) {
        int t  = i / (NP * 3);
        int pc = i - t * (NP * 3);
        int p  = pc / 3;
        int cc = pc - p * 3;
        const float* row = &secart[cc][t * NE];
        float s = 0.0f;
        #pragma unroll
        for (int j = 0; j < 9; ++j) {
            int es = stab[p * 9 + j];
            int e  = (es < 0 ? -es : es) - 1;
            float v = row[e];
            s += (es > 0) ? v : -v;
        }
        out[t0g * NP * 3 + i] = s * einv[p];   // contiguous 480-float range
    }
}

extern "C" void kernel_launch(void* const* d_in, const int* in_sizes, int n_in,
                              void* d_out, int out_size, void* d_ws, size_t ws_size,
                              hipStream_t stream) {
    const float* D_V  = (const float*)d_in[0];
    const float* logm = (const float*)d_in[1];
    const float* W1   = (const float*)d_in[2];
    const float* b1   = (const float*)d_in[3];
    const float* W2   = (const float*)d_in[4];
    const float* b2   = (const float*)d_in[5];
    const float* W3   = (const float*)d_in[6];
    const float* b3   = (const float*)d_in[7];
    const int* senders   = (const int*)d_in[8];
    const int* receivers = (const int*)d_in[9];

    int nedges = in_sizes[8];               // 45
    int ntime  = in_sizes[0] / 3 / nedges;  // 100000

    int nblocks = (ntime + TS - 1) / TS;    // 6250
    learn_forces_kernel<<<nblocks, BLOCK, 0, stream>>>(
        D_V, logm, W1, b1, W2, b2, W3, b3, senders, receivers,
        (float*)d_out, ntime);
}

// Round 8
// 207.749 us; speedup vs baseline: 1.1044x; 1.1044x over previous
//
#include <hip/hip_runtime.h>
#include <hip/hip_bf16.h>
#include <math.h>

#define NP 10
#define NE 45
#define TS 16                      // timesteps per block
#define EPB (TS * NE)              // 720 edges per block
#define BLOCK 256
#define NCHUNK ((EPB + 63) / 64)   // 12 chunks of 64 edge-slots

typedef __attribute__((ext_vector_type(8))) short short8;   // 8 bf16 MFMA frag
typedef __attribute__((ext_vector_type(4))) float f32x4;

#define C2LOG2E 2.885390081777927f   // 2*log2(e), folded into W1/W2/b1/b2
#define PI_F    3.14159265358979f
#define PIO2_F  1.57079632679490f

__device__ __forceinline__ float rcp_fast(float x) { return __builtin_amdgcn_rcpf(x); }

// s already scaled by 2*log2(e) and bias-included: tanh = 1 - 2/(2^s + 1)
__device__ __forceinline__ float tanh_pre(float s) {
    float e = __builtin_amdgcn_exp2f(s);
    return fmaf(-2.0f, rcp_fast(e + 1.0f), 1.0f);
}

__device__ __forceinline__ short bf16_rne(float f) {
    unsigned int u = __float_as_uint(f);
    return (short)((u + 0x7fffu + ((u >> 16) & 1u)) >> 16);
}
// pack two floats as bf16x2 (round-half-up) via v_perm: lo = a, hi = b
__device__ __forceinline__ int bf16pk(float a, float b) {
    unsigned int ua = __float_as_uint(a) + 0x8000u;
    unsigned int ub = __float_as_uint(b) + 0x8000u;
    return (int)__builtin_amdgcn_perm(ub, ua, 0x07060302u);
}
__device__ __forceinline__ int bperm_i(int idx_bytes, int v) {
    return __builtin_amdgcn_ds_bpermute(idx_bytes, v);
}

// bf16-accuracy branch-free acos (A&S 4.4.45, |err| < 2e-4 rad)
__device__ __forceinline__ float acos_fast(float w) {
    float a = fabsf(w);
    float s = sqrtf(1.0f - a);
    float p = fmaf(a, fmaf(a, fmaf(a, -0.0187293f, 0.0742610f), -0.2121144f), 1.5707288f);
    float v = s * p;
    return (w >= 0.0f) ? v : PI_F - v;
}
// bf16-accuracy branch-free atan2 (A&S 4.4.49 poly, |err| ~1e-5)
__device__ __forceinline__ float atan2_fast(float y, float x) {
    float ax = fabsf(x), ay = fabsf(y);
    float mx = fmaxf(ax, ay), mn = fminf(ax, ay);
    float t  = mn * rcp_fast(mx);
    float s  = t * t;
    float p  = fmaf(s, fmaf(s, fmaf(s, fmaf(s, 0.0208351f, -0.0851330f),
                                       0.1801410f), -0.3302995f), 0.9998660f);
    float rr = p * t;
    rr = (ay > ax)   ? PIO2_F - rr : rr;
    rr = (x < 0.0f)  ? PI_F  - rr : rr;
    return __builtin_copysignf(rr, y);
}

// launch_bounds(.,4): R7's (.,6) made the compiler spill loop-invariant weight
// frags to scratch (WRITE_SIZE 11.7->149 MB, VALUBusy 79->67). 4 is the proven
// no-spill config (R6: VGPR 48, clean traffic).
__global__ __launch_bounds__(BLOCK, 4) void
learn_forces_kernel(const float* __restrict__ D_V, const float* __restrict__ logm,
                    const float* __restrict__ W1, const float* __restrict__ b1,
                    const float* __restrict__ W2, const float* __restrict__ b2,
                    const float* __restrict__ W3, const float* __restrict__ b3,
                    const int* __restrict__ senders, const int* __restrict__ receivers,
                    float* __restrict__ out, int ntime)
{
    __shared__ float einv[NP];
    __shared__ int   stab[NP * 9];            // signed edge list per planet: +-(e+1)
    __shared__ int   mpair[NE];               // packed bf16 (lo=lm_recv, hi=lm_send)
    __shared__ float secart[3][EPB];          // SoA cartesian edge forces (8.64 KB)

    const int tid  = threadIdx.x;
    const int wv   = tid >> 6, lane = tid & 63;
    const int m    = lane & 15, q = lane >> 4;

    if (tid < NP) {
        float l = fminf(12.0f, fmaxf(-12.0f, logm[tid]));
        einv[tid] = __expf(-l);
    }
    if (tid < NE) {
        float lr = fminf(12.0f, fmaxf(-12.0f, logm[receivers[tid]]));
        float ls = fminf(12.0f, fmaxf(-12.0f, logm[senders[tid]]));
        mpair[tid] = bf16pk(lr, ls);
    }
    if (tid < NP) {                           // signed edge table (9 per planet)
        int cnt = 0;
        for (int e = 0; e < NE; ++e) {
            if (receivers[e] == tid) stab[tid * 9 + cnt++] =  (e + 1);
            if (senders[e]   == tid) stab[tid * 9 + cnt++] = -(e + 1);
        }
        for (; cnt < 9; ++cnt) stab[tid * 9 + cnt] = 0;
    }

    // ---- M-permuted weight fragments (invariant: lane's C-regs == next B-frag)
    const int nm = 8 * (m >> 2) + (m & 3);   // + 4t below
    short8 a1[2], a2[2], a3;
    f32x4  cb1[2], cb2[2], cb3;
    #pragma unroll
    for (int t = 0; t < 2; ++t) {
        const int n = nm + 4 * t;
        #pragma unroll
        for (int j = 0; j < 8; ++j) {
            int k = 8 * q + j;
            a1[t][j] = (k < 5) ? bf16_rne(W1[k * 32 + n] * C2LOG2E) : (short)0;
            a2[t][j] = bf16_rne(W2[k * 32 + n] * C2LOG2E);
        }
        #pragma unroll
        for (int r = 0; r < 4; ++r) {
            int nn = 8 * q + 4 * t + r;
            cb1[t][r] = b1[nn] * C2LOG2E;
            cb2[t][r] = b2[nn] * C2LOG2E;
        }
    }
    // L3 with W3 columns replicated across row-quads: A3[row][k] = W3[k][row&3]
    // => every lane's d3[g] regs 0..2 hold (e0,e1,e2) of edge 16g+m directly.
    {
        const int c3 = m & 3;
        #pragma unroll
        for (int j = 0; j < 8; ++j)
            a3[j] = (c3 < 3) ? bf16_rne(W3[(8 * q + j) * 3 + c3]) : (short)0;
        #pragma unroll
        for (int r = 0; r < 4; ++r)
            cb3[r] = (r < 3) ? b3[r] : 0.0f;
    }

    const int bpm = m * 4;                   // bperm idx base: source lane (g<<4)|m
    __syncthreads();

    // software prefetch of first chunk's D_V
    const long ebase = (long)blockIdx.x * EPB;
    float xn = 1.f, yn = 0.f, zn = 0.f;
    {
        int e0i = wv * 64 + lane;
        if (e0i < EPB) {
            const float* dv = D_V + (ebase + e0i) * 3;
            xn = dv[0]; yn = dv[1]; zn = dv[2];
        }
    }

    for (int c = wv; c < NCHUNK; c += 4) {
        const int  e_loc  = c * 64 + lane;
        const bool active = e_loc < EPB;

        float x = xn, y = yn, z = zn;
        // prefetch next chunk
        xn = 1.f; yn = 0.f; zn = 0.f;
        {
            int enx = (c + 4) * 64 + lane;
            if (c + 4 < NCHUNK && enx < EPB) {
                const float* dv = D_V + (ebase + enx) * 3;
                xn = dv[0]; yn = dv[1]; zn = dv[2];
            }
        }

        // ---- own-edge features (fast math, bf16-accuracy) ----------------
        const int le = e_loc % NE;
        float r  = sqrtf(x * x + y * y + z * z);
        float zr = fminf(1.0f, fmaxf(-1.0f, z * rcp_fast(r)));
        float th = acos_fast(zr);
        float ph = atan2_fast(y, x);

        // pack features as bf16 pairs BEFORE transport (3 ints carry 5 features)
        int mp   = mpair[le];                              // lo=lmr, hi=lms
        int p_rt = bf16pk(r, th);                          // k0,k1
        int p_pm = (int)__builtin_amdgcn_perm(             // lo=ph (k2), hi=lmr (k3)
                       (unsigned)mp, __float_as_uint(ph) + 0x8000u, 0x05040302u);
        int p_s0 = ((unsigned)mp) >> 16;                   // lo=lms (k4), hi=0

        // ---- S1: 12 bperms move all 4 groups' B-rows (one latency hop) ---
        int b0[4], b1g[4], b2g[4];
        #pragma unroll
        for (int g = 0; g < 4; ++g) {
            const int idx = bpm + g * 64;
            b0[g]  = bperm_i(idx, p_rt);
            b1g[g] = bperm_i(idx, p_pm);
            b2g[g] = bperm_i(idx, p_s0);
        }

        // ---- S2: L1 MFMAs (A zeros at k>=5 mask garbage B rows) ----------
        f32x4 d0[4], d1[4];
        #pragma unroll
        for (int g = 0; g < 4; ++g) {
            short8 bf1;
            int* bi = (int*)&bf1;
            bi[0] = b0[g]; bi[1] = b1g[g]; bi[2] = b2g[g]; bi[3] = 0;
            d0[g] = __builtin_amdgcn_mfma_f32_16x16x32_bf16(a1[0], bf1, cb1[0], 0, 0, 0);
            d1[g] = __builtin_amdgcn_mfma_f32_16x16x32_bf16(a1[1], bf1, cb1[1], 0, 0, 0);
        }

        // ---- S3: tanh + L2 MFMAs -----------------------------------------
        #pragma unroll
        for (int g = 0; g < 4; ++g) {
            short8 bh;
            int* hb = (int*)&bh;
            float h0 = tanh_pre(d0[g][0]), h1 = tanh_pre(d0[g][1]);
            float h2 = tanh_pre(d0[g][2]), h3 = tanh_pre(d0[g][3]);
            float h4 = tanh_pre(d1[g][0]), h5 = tanh_pre(d1[g][1]);
            float h6 = tanh_pre(d1[g][2]), h7 = tanh_pre(d1[g][3]);
            hb[0] = bf16pk(h0, h1); hb[1] = bf16pk(h2, h3);
            hb[2] = bf16pk(h4, h5); hb[3] = bf16pk(h6, h7);
            d0[g] = __builtin_amdgcn_mfma_f32_16x16x32_bf16(a2[0], bh, cb2[0], 0, 0, 0);
            d1[g] = __builtin_amdgcn_mfma_f32_16x16x32_bf16(a2[1], bh, cb2[1], 0, 0, 0);
        }

        // ---- S4: tanh + L3 MFMAs -----------------------------------------
        f32x4 d3[4];
        #pragma unroll
        for (int g = 0; g < 4; ++g) {
            short8 bh;
            int* hb = (int*)&bh;
            float h0 = tanh_pre(d0[g][0]), h1 = tanh_pre(d0[g][1]);
            float h2 = tanh_pre(d0[g][2]), h3 = tanh_pre(d0[g][3]);
            float h4 = tanh_pre(d1[g][0]), h5 = tanh_pre(d1[g][1]);
            float h6 = tanh_pre(d1[g][2]), h7 = tanh_pre(d1[g][3]);
            hb[0] = bf16pk(h0, h1); hb[1] = bf16pk(h2, h3);
            hb[2] = bf16pk(h4, h5); hb[3] = bf16pk(h6, h7);
            d3[g] = __builtin_amdgcn_mfma_f32_16x16x32_bf16(a3, bh, cb3, 0, 0, 0);
        }

        // ---- S5: own-group register select (no transport needed) ---------
        float e0a = (q & 1) ? d3[1][0] : d3[0][0], e0b = (q & 1) ? d3[3][0] : d3[2][0];
        float e1a = (q & 1) ? d3[1][1] : d3[0][1], e1b = (q & 1) ? d3[3][1] : d3[2][1];
        float e2a = (q & 1) ? d3[1][2] : d3[0][2], e2b = (q & 1) ? d3[3][2] : d3[2][2];
        float e0 = (q & 2) ? e0b : e0a;
        float e1 = (q & 2) ? e1b : e1a;
        float e2 = (q & 2) ? e2b : e2a;

        // ---- sph -> cart, plain SoA LDS store (no atomics) ---------------
        float st = __sinf(e1), ct = __cosf(e1);
        float sp = __sinf(e2), cp = __cosf(e2);
        if (active) {
            secart[0][e_loc] = e0 * st * cp;
            secart[1][e_loc] = e0 * st * sp;
            secart[2][e_loc] = e0 * ct;
        }
    }
    __syncthreads();

    // ---- table-driven signed gather-sum: one (t, planet, comp) per thread
    const long t0g = (long)blockIdx.x * TS;
    for (int i = tid; i < TS * NP * 3; i += BLOCK) {
        int t  = i / (NP * 3);
        int pc = i - t * (NP * 3);
        int p  = pc / 3;
        int cc = pc - p * 3;
        const float* row = &secart[cc][t * NE];
        float s = 0.0f;
        #pragma unroll
        for (int j = 0; j < 9; ++j) {
            int es = stab[p * 9 + j];
            int e  = (es < 0 ? -es : es) - 1;
            float v = row[e];
            s += (es > 0) ? v : -v;
        }
        out[t0g * NP * 3 + i] = s * einv[p];   // contiguous 480-float range
    }
}

extern "C" void kernel_launch(void* const* d_in, const int* in_sizes, int n_in,
                              void* d_out, int out_size, void* d_ws, size_t ws_size,
                              hipStream_t stream) {
    const float* D_V  = (const float*)d_in[0];
    const float* logm = (const float*)d_in[1];
    const float* W1   = (const float*)d_in[2];
    const float* b1   = (const float*)d_in[3];
    const float* W2   = (const float*)d_in[4];
    const float* b2   = (const float*)d_in[5];
    const float* W3   = (const float*)d_in[6];
    const float* b3   = (const float*)d_in[7];
    const int* senders   = (const int*)d_in[8];
    const int* receivers = (const int*)d_in[9];

    int nedges = in_sizes[8];               // 45
    int ntime  = in_sizes[0] / 3 / nedges;  // 100000

    int nblocks = (ntime + TS - 1) / TS;    // 6250
    learn_forces_kernel<<<nblocks, BLOCK, 0, stream>>>(
        D_V, logm, W1, b1, W2, b2, W3, b3, senders, receivers,
        (float*)d_out, ntime);
}

// Round 9
// 205.391 us; speedup vs baseline: 1.1171x; 1.0115x over previous
//
#include <hip/hip_runtime.h>
#include <hip/hip_bf16.h>
#include <math.h>

#define NP 10
#define NE 45
#define TS 16                      // timesteps per block
#define EPB (TS * NE)              // 720 edges per block
#define BLOCK 256
#define NCHUNK ((EPB + 63) / 64)   // 12 chunks of 64 edge-slots

typedef __attribute__((ext_vector_type(8))) short short8;   // 8 bf16 MFMA frag
typedef __attribute__((ext_vector_type(4))) float f32x4;

#define C2LOG2E 2.885390081777927f   // 2*log2(e), folded into W1/W2/b1/b2
#define PI_F    3.14159265358979f
#define PIO2_F  1.57079632679490f

__device__ __forceinline__ float rcp_fast(float x) { return __builtin_amdgcn_rcpf(x); }

// Pair of tanh with ONE shared rcp: 1/(e0+1) = rcp((e0+1)(e1+1))*(e1+1).
// Safe: s<=|2.885*12|+slack -> e+1 <= 2^35, product <= 2^70 < fp32 max.
// s is pre-scaled by 2*log2(e) with bias folded into MFMA C-init.
__device__ __forceinline__ void tanh_pair(float s0, float s1, float& t0, float& t1) {
    float f0 = __builtin_amdgcn_exp2f(s0) + 1.0f;
    float f1 = __builtin_amdgcn_exp2f(s1) + 1.0f;
    float r  = rcp_fast(f0 * f1);
    t0 = fmaf(-2.0f, r * f1, 1.0f);
    t1 = fmaf(-2.0f, r * f0, 1.0f);
}

__device__ __forceinline__ short bf16_rne(float f) {
    unsigned int u = __float_as_uint(f);
    return (short)((u + 0x7fffu + ((u >> 16) & 1u)) >> 16);
}
// pack two floats as bf16x2 (round-half-up) via v_perm: lo = a, hi = b
__device__ __forceinline__ int bf16pk(float a, float b) {
    unsigned int ua = __float_as_uint(a) + 0x8000u;
    unsigned int ub = __float_as_uint(b) + 0x8000u;
    return (int)__builtin_amdgcn_perm(ub, ua, 0x07060302u);
}
__device__ __forceinline__ int bperm_i(int idx_bytes, int v) {
    return __builtin_amdgcn_ds_bpermute(idx_bytes, v);
}

// bf16-accuracy branch-free acos (A&S 4.4.45, |err| < 2e-4 rad)
__device__ __forceinline__ float acos_fast(float w) {
    float a = fabsf(w);
    float s = sqrtf(1.0f - a);
    float p = fmaf(a, fmaf(a, fmaf(a, -0.0187293f, 0.0742610f), -0.2121144f), 1.5707288f);
    float v = s * p;
    return (w >= 0.0f) ? v : PI_F - v;
}
// bf16-accuracy branch-free atan2 (A&S 4.4.49 poly, |err| ~1e-5)
__device__ __forceinline__ float atan2_fast(float y, float x) {
    float ax = fabsf(x), ay = fabsf(y);
    float mx = fmaxf(ax, ay), mn = fminf(ax, ay);
    float t  = mn * rcp_fast(mx);
    float s  = t * t;
    float p  = fmaf(s, fmaf(s, fmaf(s, fmaf(s, 0.0208351f, -0.0851330f),
                                       0.1801410f), -0.3302995f), 0.9998660f);
    float rr = p * t;
    rr = (ay > ax)   ? PIO2_F - rr : rr;
    rr = (x < 0.0f)  ? PI_F  - rr : rr;
    return __builtin_copysignf(rr, y);
}

// launch_bounds(.,4): (.,6) caused scratch spill of weight frags (R7:
// WRITE_SIZE 11.7->149 MB). 4 is the proven no-spill config.
__global__ __launch_bounds__(BLOCK, 4) void
learn_forces_kernel(const float* __restrict__ D_V, const float* __restrict__ logm,
                    const float* __restrict__ W1, const float* __restrict__ b1,
                    const float* __restrict__ W2, const float* __restrict__ b2,
                    const float* __restrict__ W3, const float* __restrict__ b3,
                    const int* __restrict__ senders, const int* __restrict__ receivers,
                    float* __restrict__ out, int ntime)
{
    __shared__ float einv[NP];
    __shared__ int   stab[NP * 9];            // signed edge list per planet: +-(e+1)
    __shared__ int   mpair[NE];               // packed bf16 (lo=lm_recv, hi=lm_send)
    __shared__ float secart[3][EPB];          // SoA cartesian edge forces (8.64 KB)

    const int tid  = threadIdx.x;
    const int wv   = tid >> 6, lane = tid & 63;
    const int m    = lane & 15, q = lane >> 4;

    if (tid < NP) {
        float l = fminf(12.0f, fmaxf(-12.0f, logm[tid]));
        einv[tid] = __expf(-l);
    }
    if (tid < NE) {
        float lr = fminf(12.0f, fmaxf(-12.0f, logm[receivers[tid]]));
        float ls = fminf(12.0f, fmaxf(-12.0f, logm[senders[tid]]));
        mpair[tid] = bf16pk(lr, ls);
    }
    if (tid < NP) {                           // signed edge table (9 per planet)
        int cnt = 0;
        for (int e = 0; e < NE; ++e) {
            if (receivers[e] == tid) stab[tid * 9 + cnt++] =  (e + 1);
            if (senders[e]   == tid) stab[tid * 9 + cnt++] = -(e + 1);
        }
        for (; cnt < 9; ++cnt) stab[tid * 9 + cnt] = 0;
    }

    // ---- M-permuted weight fragments (invariant: lane's C-regs == next B-frag)
    const int nm = 8 * (m >> 2) + (m & 3);   // + 4t below
    short8 a1[2], a2[2], a3;
    f32x4  cb1[2], cb2[2], cb3;
    #pragma unroll
    for (int t = 0; t < 2; ++t) {
        const int n = nm + 4 * t;
        #pragma unroll
        for (int j = 0; j < 8; ++j) {
            int k = 8 * q + j;
            a1[t][j] = (k < 5) ? bf16_rne(W1[k * 32 + n] * C2LOG2E) : (short)0;
            a2[t][j] = bf16_rne(W2[k * 32 + n] * C2LOG2E);
        }
        #pragma unroll
        for (int r = 0; r < 4; ++r) {
            int nn = 8 * q + 4 * t + r;
            cb1[t][r] = b1[nn] * C2LOG2E;
            cb2[t][r] = b2[nn] * C2LOG2E;
        }
    }
    // L3 with W3 columns replicated across row-quads: A3[row][k] = W3[k][row&3]
    // => every lane's d3[g] regs 0..2 hold (e0,e1,e2) of edge 16g+m directly.
    {
        const int c3 = m & 3;
        #pragma unroll
        for (int j = 0; j < 8; ++j)
            a3[j] = (c3 < 3) ? bf16_rne(W3[(8 * q + j) * 3 + c3]) : (short)0;
        #pragma unroll
        for (int r = 0; r < 4; ++r)
            cb3[r] = (r < 3) ? b3[r] : 0.0f;
    }

    const int bpm = m * 4;                   // bperm idx base: source lane (g<<4)|m
    __syncthreads();

    // software prefetch of first chunk's D_V
    const long ebase = (long)blockIdx.x * EPB;
    float xn = 1.f, yn = 0.f, zn = 0.f;
    {
        int e0i = wv * 64 + lane;
        if (e0i < EPB) {
            const float* dv = D_V + (ebase + e0i) * 3;
            xn = dv[0]; yn = dv[1]; zn = dv[2];
        }
    }

    for (int c = wv; c < NCHUNK; c += 4) {
        const int  e_loc  = c * 64 + lane;
        const bool active = e_loc < EPB;

        float x = xn, y = yn, z = zn;
        // prefetch next chunk
        xn = 1.f; yn = 0.f; zn = 0.f;
        {
            int enx = (c + 4) * 64 + lane;
            if (c + 4 < NCHUNK && enx < EPB) {
                const float* dv = D_V + (ebase + enx) * 3;
                xn = dv[0]; yn = dv[1]; zn = dv[2];
            }
        }

        // ---- own-edge features: one rsqrt serves both r and z/r ----------
        const int le = e_loc % NE;
        float ss  = fmaf(x, x, fmaf(y, y, z * z));
        float rsq = __builtin_amdgcn_rsqf(ss);
        float r   = ss * rsq;
        float zr  = fminf(1.0f, fmaxf(-1.0f, z * rsq));
        float th  = acos_fast(zr);
        float ph  = atan2_fast(y, x);

        // pack features as bf16 pairs BEFORE transport (3 ints carry 5 features)
        int mp   = mpair[le];                              // lo=lmr, hi=lms
        int p_rt = bf16pk(r, th);                          // k0,k1
        int p_pm = (int)__builtin_amdgcn_perm(             // lo=ph (k2), hi=lmr (k3)
                       (unsigned)mp, __float_as_uint(ph) + 0x8000u, 0x05040302u);
        int p_s0 = ((unsigned)mp) >> 16;                   // lo=lms (k4), hi=0

        // ---- S1: 12 bperms move all 4 groups' B-rows (one latency hop) ---
        int b0[4], b1g[4], b2g[4];
        #pragma unroll
        for (int g = 0; g < 4; ++g) {
            const int idx = bpm + g * 64;
            b0[g]  = bperm_i(idx, p_rt);
            b1g[g] = bperm_i(idx, p_pm);
            b2g[g] = bperm_i(idx, p_s0);
        }

        // ---- S2: L1 MFMAs (A zeros at k>=5 mask garbage B rows) ----------
        f32x4 d0[4], d1[4];
        #pragma unroll
        for (int g = 0; g < 4; ++g) {
            short8 bf1;
            int* bi = (int*)&bf1;
            bi[0] = b0[g]; bi[1] = b1g[g]; bi[2] = b2g[g]; bi[3] = 0;
            d0[g] = __builtin_amdgcn_mfma_f32_16x16x32_bf16(a1[0], bf1, cb1[0], 0, 0, 0);
            d1[g] = __builtin_amdgcn_mfma_f32_16x16x32_bf16(a1[1], bf1, cb1[1], 0, 0, 0);
        }

        // ---- S3: paired tanh + L2 MFMAs ----------------------------------
        #pragma unroll
        for (int g = 0; g < 4; ++g) {
            short8 bh;
            int* hb = (int*)&bh;
            float h0, h1, h2, h3, h4, h5, h6, h7;
            tanh_pair(d0[g][0], d0[g][1], h0, h1);
            tanh_pair(d0[g][2], d0[g][3], h2, h3);
            tanh_pair(d1[g][0], d1[g][1], h4, h5);
            tanh_pair(d1[g][2], d1[g][3], h6, h7);
            hb[0] = bf16pk(h0, h1); hb[1] = bf16pk(h2, h3);
            hb[2] = bf16pk(h4, h5); hb[3] = bf16pk(h6, h7);
            d0[g] = __builtin_amdgcn_mfma_f32_16x16x32_bf16(a2[0], bh, cb2[0], 0, 0, 0);
            d1[g] = __builtin_amdgcn_mfma_f32_16x16x32_bf16(a2[1], bh, cb2[1], 0, 0, 0);
        }

        // ---- S4: paired tanh + L3 MFMAs ----------------------------------
        f32x4 d3[4];
        #pragma unroll
        for (int g = 0; g < 4; ++g) {
            short8 bh;
            int* hb = (int*)&bh;
            float h0, h1, h2, h3, h4, h5, h6, h7;
            tanh_pair(d0[g][0], d0[g][1], h0, h1);
            tanh_pair(d0[g][2], d0[g][3], h2, h3);
            tanh_pair(d1[g][0], d1[g][1], h4, h5);
            tanh_pair(d1[g][2], d1[g][3], h6, h7);
            hb[0] = bf16pk(h0, h1); hb[1] = bf16pk(h2, h3);
            hb[2] = bf16pk(h4, h5); hb[3] = bf16pk(h6, h7);
            d3[g] = __builtin_amdgcn_mfma_f32_16x16x32_bf16(a3, bh, cb3, 0, 0, 0);
        }

        // ---- S5: own-group register select (no transport needed) ---------
        float e0a = (q & 1) ? d3[1][0] : d3[0][0], e0b = (q & 1) ? d3[3][0] : d3[2][0];
        float e1a = (q & 1) ? d3[1][1] : d3[0][1], e1b = (q & 1) ? d3[3][1] : d3[2][1];
        float e2a = (q & 1) ? d3[1][2] : d3[0][2], e2b = (q & 1) ? d3[3][2] : d3[2][2];
        float e0 = (q & 2) ? e0b : e0a;
        float e1 = (q & 2) ? e1b : e1a;
        float e2 = (q & 2) ? e2b : e2a;

        // ---- sph -> cart, plain SoA LDS store (no atomics) ---------------
        float st = __sinf(e1), ct = __cosf(e1);
        float sp = __sinf(e2), cp = __cosf(e2);
        if (active) {
            secart[0][e_loc] = e0 * st * cp;
            secart[1][e_loc] = e0 * st * sp;
            secart[2][e_loc] = e0 * ct;
        }
    }
    __syncthreads();

    // ---- table-driven signed gather-sum: one (t, planet, comp) per thread
    const long t0g = (long)blockIdx.x * TS;
    for (int i = tid; i < TS * NP * 3; i += BLOCK) {
        int t  = i / (NP * 3);
        int pc = i - t * (NP * 3);
        int p  = pc / 3;
        int cc = pc - p * 3;
        const float* row = &secart[cc][t * NE];
        float s = 0.0f;
        #pragma unroll
        for (int j = 0; j < 9; ++j) {
            int es = stab[p * 9 + j];
            int e  = (es < 0 ? -es : es) - 1;
            float v = row[e];
            s += (es > 0) ? v : -v;
        }
        out[t0g * NP * 3 + i] = s * einv[p];   // contiguous 480-float range
    }
}

extern "C" void kernel_launch(void* const* d_in, const int* in_sizes, int n_in,
                              void* d_out, int out_size, void* d_ws, size_t ws_size,
                              hipStream_t stream) {
    const float* D_V  = (const float*)d_in[0];
    const float* logm = (const float*)d_in[1];
    const float* W1   = (const float*)d_in[2];
    const float* b1   = (const float*)d_in[3];
    const float* W2   = (const float*)d_in[4];
    const float* b2   = (const float*)d_in[5];
    const float* W3   = (const float*)d_in[6];
    const float* b3   = (const float*)d_in[7];
    const int* senders   = (const int*)d_in[8];
    const int* receivers = (const int*)d_in[9];

    int nedges = in_sizes[8];               // 45
    int ntime  = in_sizes[0] / 3 / nedges;  // 100000

    int nblocks = (ntime + TS - 1) / TS;    // 6250
    learn_forces_kernel<<<nblocks, BLOCK, 0, stream>>>(
        D_V, logm, W1, b1, W2, b2, W3, b3, senders, receivers,
        (float*)d_out, ntime);
}